// Round 2
// baseline (547.263 us; speedup 1.0000x reference)
//
#include <hip/hip_runtime.h>

#define HH 128
#define WW 128
#define CC 64
#define BS 1024
#define RS (WW * CC)    // row stride in floats

typedef float f4 __attribute__((ext_vector_type(4)));

static __device__ __forceinline__ f4 vload(const float* __restrict__ p) {
    return *reinterpret_cast<const f4*>(p);
}
static __device__ __forceinline__ void vstore(float* p, f4 v) {
    *reinterpret_cast<f4*>(p) = v;
}
static __device__ __forceinline__ f4 vrelu(f4 a) {
    f4 r;
    #pragma unroll
    for (int i = 0; i < 4; ++i) r[i] = fmaxf(a[i], 0.f);
    return r;
}
static __device__ __forceinline__ f4 vrsq_eps(f4 a) {   // 1/sqrt(a+eps), HW approx
    f4 r;
    #pragma unroll
    for (int i = 0; i < 4; ++i) r[i] = __builtin_amdgcn_rsqf(a[i] + 1e-3f);
    return r;
}
static __device__ __forceinline__ f4 vrcp(f4 a) {       // 1/a, HW approx
    f4 r;
    #pragma unroll
    for (int i = 0; i < 4; ++i) r[i] = __builtin_amdgcn_rcpf(a[i]);
    return r;
}

// 3x3 depthwise conv over 4 kernels, 2 w-points, 4 channels, branch-free body.
// HAS_M/HAS_P: whether rows h-1 / h+1 exist (compile-time).
template<bool HAS_M, bool HAS_P>
static __device__ __forceinline__ void conv3x3(
    const float* __restrict__ rowc,
    long om, long o0, long o1, long op, bool zl, bool zr,
    const float* __restrict__ kg,  const float* __restrict__ kg1,
    const float* __restrict__ kDx, const float* __restrict__ kDy, int c4,
    f4 acc[4][2], f4& fin0, f4& fin1)
{
    #pragma unroll
    for (int r = 0; r < 3; ++r) {
        const bool has = (r == 0) ? HAS_M : (r == 2 ? HAS_P : true);   // folds per unrolled r
        if (has) {
            const float* rp = rowc + (long)(r - 1) * RS;
            f4 in[4];
            in[0] = vload(rp + om);      // clamped addr; zeroed below if OOB
            in[1] = vload(rp + o0);
            in[2] = vload(rp + o1);
            in[3] = vload(rp + op);
            if (zl) in[0] = (f4)0.f;     // cndmask, no divergence cost
            if (zr) in[3] = (f4)0.f;
            if (r == 1) { fin0 = in[1]; fin1 = in[2]; }
            #pragma unroll
            for (int dw = 0; dw < 3; ++dw) {
                const int k = r * 3 + dw;
                const f4 w_g  = vload(kg  + k * CC + c4);
                const f4 w_g1 = vload(kg1 + k * CC + c4);
                const f4 w_dx = vload(kDx + k * CC + c4);
                const f4 w_dy = vload(kDy + k * CC + c4);
                acc[0][0] += in[dw] * w_g;   acc[0][1] += in[dw + 1] * w_g;
                acc[1][0] += in[dw] * w_g1;  acc[1][1] += in[dw + 1] * w_g1;
                acc[2][0] += in[dw] * w_dx;  acc[2][1] += in[dw + 1] * w_dx;
                acc[3][0] += in[dw] * w_dy;  acc[3][1] += in[dw + 1] * w_dy;
            }
        }
    }
}

// __launch_bounds__(1024, 8): 8 waves/EU = 2 blocks/CU -> caps VGPR at 64
__global__ __launch_bounds__(BS, 8) void diffusion_fused(
    const float* __restrict__ s0,
    const float* __restrict__ kg,  const float* __restrict__ kg1,
    const float* __restrict__ kDx, const float* __restrict__ kDy,
    const float* __restrict__ bng,  const float* __restrict__ bng1,
    const float* __restrict__ bnDx, const float* __restrict__ bnDy,
    const float* __restrict__ bn_out,
    float* __restrict__ out)
{
    __shared__ float Lg[RS];   // 32 KB: g row; reused as h1 buffer
    __shared__ float Lh[RS];   // 32 KB: h0(=f) row

    const int t  = threadIdx.x;
    const int c4 = (t & 15) << 2;        // channels c4..c4+3 (16-lane clusters coalesce)
    const int w0 = (t >> 4) << 1;        // w pair (w0, w0+1)
    const int l  = t & 63;
    const int lm = (l & 48) | ((l + 15) & 15);   // channel-roll shuffles within 16-lane group
    const int lp = (l & 48) | ((l + 1)  & 15);

    // bijective XCD swizzle: 2048 blocks = 8 XCDs x 256 contiguous rows
    const int bid = blockIdx.x;
    const int bh  = ((bid & 7) << 8) | (bid >> 3);
    const int hrow = bh & (HH - 1);
    const long rowbase = (long)bh * RS;

    // clamped column offsets (valid addresses even at W edges)
    const long o0 = (long)w0 * CC + c4;
    const long o1 = o0 + CC;
    const long om = (long)((w0 > 0)      ? (w0 - 1) : 0)      * CC + c4;
    const long op = (long)((w0 < WW - 2) ? (w0 + 2) : (WW - 1)) * CC + c4;
    const bool zl = (w0 == 0);
    const bool zr = (w0 == WW - 2);

    // ---- phase 1a: conv (branch-free interior path) ----
    f4 acc[4][2];
    #pragma unroll
    for (int q = 0; q < 4; ++q) { acc[q][0] = (f4)0.f; acc[q][1] = (f4)0.f; }
    f4 fin0 = (f4)0.f, fin1 = (f4)0.f;
    const float* rowc = s0 + rowbase;

    if (hrow > 0 && hrow < HH - 1)
        conv3x3<true, true >(rowc, om, o0, o1, op, zl, zr, kg, kg1, kDx, kDy, c4, acc, fin0, fin1);
    else if (hrow == 0)
        conv3x3<false, true >(rowc, om, o0, o1, op, zl, zr, kg, kg1, kDx, kDy, c4, acc, fin0, fin1);
    else
        conv3x3<true, false>(rowc, om, o0, o1, op, zl, zr, kg, kg1, kDx, kDy, c4, acc, fin0, fin1);

    // ---- BN folds: y = S*x + B, optional positive scale folded in ----
    #define BNFOLD(P, S, B, SC) { \
        const f4 ga  = vload((P) + c4);        \
        const f4 be  = vload((P) + 64 + c4);   \
        const f4 mu  = vload((P) + 128 + c4);  \
        const f4 va  = vload((P) + 192 + c4);  \
        const f4 sc0 = ga * vrsq_eps(va);      \
        S = sc0 * (SC);                        \
        B = (be - mu * sc0) * (SC); }

    f4 s_g, b_g, s_g1, b_g1, s_dx, b_dx, s_dy, b_dy;
    BNFOLD(bng,  s_g,  b_g,  1.0f);
    BNFOLD(bng1, s_g1, b_g1, 1.0f);
    BNFOLD(bnDx, s_dx, b_dx, 0.4f);   // 2*DT folded: tbx = 2*Bx directly
    BNFOLD(bnDy, s_dy, b_dy, 0.4f);

    // ---- g, g1 + publish LDS rows ASAP ----
    f4 gq[2], g1q[2], hq[2];
    gq[0]  = vrelu(acc[0][0] * s_g  + b_g );
    gq[1]  = vrelu(acc[0][1] * s_g  + b_g );
    g1q[0] = vrelu(acc[1][0] * s_g1 + b_g1);
    g1q[1] = vrelu(acc[1][1] * s_g1 + b_g1);
    hq[0] = fin0; hq[1] = fin1;
    vstore(&Lg[(w0    ) * CC + c4], gq[0]);
    vstore(&Lg[(w0 + 1) * CC + c4], gq[1]);
    vstore(&Lh[(w0    ) * CC + c4], fin0);
    vstore(&Lh[(w0 + 1) * CC + c4], fin1);

    // ---- PDE coefficients (between store and barrier: overlaps other waves) ----
    f4 cWm[2], cWp[2], cCm[2], cCp[2], A0[2], PqD[2], vy[2];
    #pragma unroll
    for (int wi = 0; wi < 2; ++wi) {
        const f4 tbx = vrelu(acc[2][wi] * s_dx + b_dx);   // = 2*DT*Dx
        const f4 tby = vrelu(acc[3][wi] * s_dy + b_dy);   // = 2*DT*Dy
        // vy = 0.5*(g1[c-1] - g1[c+1]) wrap: in-quad + 2 shuffles
        const f4 g1v = g1q[wi];
        const float cm3 = __shfl(g1v.w, lm);
        const float cp0 = __shfl(g1v.x, lp);
        f4 cm, cp;
        cm.x = cm3;   cm.y = g1v.x; cm.z = g1v.y; cm.w = g1v.z;
        cp.x = g1v.y; cp.y = g1v.z; cp.z = g1v.w; cp.w = cp0;
        vy[wi] = 0.5f * (cm - cp);
        const f4 Dv = vrcp((f4)1.f + tbx + tby);
        const f4 Ax = gq[wi]  * 0.2f;
        const f4 Ay = g1q[wi] * 0.2f;
        cWm[wi] = Dv * (tbx - Ax);            // coeff of h[w-1]
        cWp[wi] = Dv * (tbx + Ax);            // coeff of h[w+1]
        cCm[wi] = Dv * (tby - Ay);            // coeff of h[c-1]
        cCp[wi] = Dv * (tby + Ay);            // coeff of h[c+1]
        A0[wi]  = Dv * hq[wi] * ((f4)1.4f - tbx - tby);   // h0==f both iters (K=2 lag)
        PqD[wi] = Dv * (-0.4f);               // cE = PqD*(ux+vy)
    }
    __syncthreads();   // barrier A: g,f visible

    // ---- phase 1b: cE from ux (W-neighbors of g wrap via LDS) ----
    f4 cE[2];
    #pragma unroll
    for (int wi = 0; wi < 2; ++wi) {
        const int w = w0 + wi;
        const f4 gm = vload(&Lg[((w - 1) & (WW - 1)) * CC + c4]);
        const f4 gp = vload(&Lg[((w + 1) & (WW - 1)) * CC + c4]);
        cE[wi] = PqD[wi] * ((f4)0.5f * (gm - gp) + vy[wi]);
    }

    // ---- PDE iter 1 (h = f, W-neighbors from Lh) ----
    f4 hn[2];
    #pragma unroll
    for (int wi = 0; wi < 2; ++wi) {
        const int w = w0 + wi;
        const f4 hm = vload(&Lh[((w - 1) & (WW - 1)) * CC + c4]);
        const f4 hp = vload(&Lh[((w + 1) & (WW - 1)) * CC + c4]);
        const f4 hv = hq[wi];
        const float m3 = __shfl(hv.w, lm);
        const float p0 = __shfl(hv.x, lp);
        f4 cm, cp;
        cm.x = m3;   cm.y = hv.x; cm.z = hv.y; cm.w = hv.z;
        cp.x = hv.y; cp.y = hv.z; cp.z = hv.w; cp.w = p0;
        hn[wi] = A0[wi] + cE[wi] * hv + cWm[wi] * hm + cWp[wi] * hp
               + cCm[wi] * cm + cCp[wi] * cp;
    }
    __syncthreads();   // barrier B: Lg(1b)/Lh(iter1) reads done
    vstore(&Lg[(w0    ) * CC + c4], hn[0]);   // Lg now holds h1
    vstore(&Lg[(w0 + 1) * CC + c4], hn[1]);
    hq[0] = hn[0]; hq[1] = hn[1];
    __syncthreads();   // barrier C: h1 visible

    // ---- PDE iter 2 (W-neighbors from Lg = h1) ----
    #pragma unroll
    for (int wi = 0; wi < 2; ++wi) {
        const int w = w0 + wi;
        const f4 hm = vload(&Lg[((w - 1) & (WW - 1)) * CC + c4]);
        const f4 hp = vload(&Lg[((w + 1) & (WW - 1)) * CC + c4]);
        const f4 hv = hq[wi];
        const float m3 = __shfl(hv.w, lm);
        const float p0 = __shfl(hv.x, lp);
        f4 cm, cp;
        cm.x = m3;   cm.y = hv.x; cm.z = hv.y; cm.w = hv.z;
        cp.x = hv.y; cp.y = hv.z; cp.z = hv.w; cp.w = p0;
        hn[wi] = A0[wi] + cE[wi] * hv + cWm[wi] * hm + cWp[wi] * hp
               + cCm[wi] * cm + cCp[wi] * cp;
    }

    // ---- epilogue: BN + ReLU, float4 store ----
    f4 s_o, b_o;
    BNFOLD(bn_out, s_o, b_o, 1.0f);
    #undef BNFOLD
    vstore(out + rowbase + o0, vrelu(hn[0] * s_o + b_o));
    vstore(out + rowbase + o1, vrelu(hn[1] * s_o + b_o));
}

extern "C" void kernel_launch(void* const* d_in, const int* in_sizes, int n_in,
                              void* d_out, int out_size, void* d_ws, size_t ws_size,
                              hipStream_t stream) {
    const float* s0   = (const float*)d_in[0];
    const float* kg   = (const float*)d_in[1];
    const float* kg1  = (const float*)d_in[2];
    const float* kDx  = (const float*)d_in[3];
    const float* kDy  = (const float*)d_in[4];
    const float* bng  = (const float*)d_in[5];
    const float* bng1 = (const float*)d_in[6];
    const float* bnDx = (const float*)d_in[7];
    const float* bnDy = (const float*)d_in[8];
    const float* bno  = (const float*)d_in[9];
    float* out = (float*)d_out;

    dim3 grid(16 * 128);   // one block per (batch, row), XCD-swizzled in-kernel
    dim3 block(BS);
    diffusion_fused<<<grid, block, 0, stream>>>(
        s0, kg, kg1, kDx, kDy, bng, bng1, bnDx, bnDy, bno, out);
}

// Round 3
// 225.030 us; speedup vs baseline: 2.4320x; 2.4320x over previous
//
#include <hip/hip_runtime.h>

#define HH 128
#define WW 128
#define CC 64
#define BS 1024
#define RS (WW * CC)    // row stride in floats

typedef float f4 __attribute__((ext_vector_type(4)));

static __device__ __forceinline__ f4 vload(const float* __restrict__ p) {
    return *reinterpret_cast<const f4*>(p);
}
static __device__ __forceinline__ void vstore(float* p, f4 v) {
    *reinterpret_cast<f4*>(p) = v;
}
static __device__ __forceinline__ f4 vrelu(f4 a) {
    f4 r;
    #pragma unroll
    for (int i = 0; i < 4; ++i) r[i] = fmaxf(a[i], 0.f);
    return r;
}
static __device__ __forceinline__ f4 vrsq_eps(f4 a) {   // 1/sqrt(a+eps), HW approx
    f4 r;
    #pragma unroll
    for (int i = 0; i < 4; ++i) r[i] = __builtin_amdgcn_rsqf(a[i] + 1e-3f);
    return r;
}
static __device__ __forceinline__ f4 vrcp(f4 a) {       // 1/a, HW approx
    f4 r;
    #pragma unroll
    for (int i = 0; i < 4; ++i) r[i] = __builtin_amdgcn_rcpf(a[i]);
    return r;
}

// 3x3 depthwise conv over 4 kernels, 2 w-points, 4 channels, branch-free body.
// HAS_M/HAS_P: whether rows h-1 / h+1 exist (compile-time).
template<bool HAS_M, bool HAS_P>
static __device__ __forceinline__ void conv3x3(
    const float* __restrict__ rowc,
    long om, long o0, long o1, long op, bool zl, bool zr,
    const float* __restrict__ kg,  const float* __restrict__ kg1,
    const float* __restrict__ kDx, const float* __restrict__ kDy, int c4,
    f4 acc[4][2], f4& fin0, f4& fin1)
{
    #pragma unroll
    for (int r = 0; r < 3; ++r) {
        const bool has = (r == 0) ? HAS_M : (r == 2 ? HAS_P : true);   // folds per unrolled r
        if (has) {
            const float* rp = rowc + (long)(r - 1) * RS;
            f4 in[4];
            in[0] = vload(rp + om);      // clamped addr; zeroed below if OOB
            in[1] = vload(rp + o0);
            in[2] = vload(rp + o1);
            in[3] = vload(rp + op);
            if (zl) in[0] = (f4)0.f;     // cndmask, no divergence cost
            if (zr) in[3] = (f4)0.f;
            if (r == 1) { fin0 = in[1]; fin1 = in[2]; }
            #pragma unroll
            for (int dw = 0; dw < 3; ++dw) {
                const int k = r * 3 + dw;
                const f4 w_g  = vload(kg  + k * CC + c4);
                const f4 w_g1 = vload(kg1 + k * CC + c4);
                const f4 w_dx = vload(kDx + k * CC + c4);
                const f4 w_dy = vload(kDy + k * CC + c4);
                acc[0][0] += in[dw] * w_g;   acc[0][1] += in[dw + 1] * w_g;
                acc[1][0] += in[dw] * w_g1;  acc[1][1] += in[dw + 1] * w_g1;
                acc[2][0] += in[dw] * w_dx;  acc[2][1] += in[dw + 1] * w_dx;
                acc[3][0] += in[dw] * w_dy;  acc[3][1] += in[dw + 1] * w_dy;
            }
        }
    }
}

// NOTE: no waves-per-EU pin — round 2 showed __launch_bounds__(1024, 8) forces
// the allocator to 32 VGPR and spills ~1.5 GB/dispatch to scratch (455 us).
// Default allocation gives 64 VGPR = 2 blocks/CU already.
__global__ __launch_bounds__(BS) void diffusion_fused(
    const float* __restrict__ s0,
    const float* __restrict__ kg,  const float* __restrict__ kg1,
    const float* __restrict__ kDx, const float* __restrict__ kDy,
    const float* __restrict__ bng,  const float* __restrict__ bng1,
    const float* __restrict__ bnDx, const float* __restrict__ bnDy,
    const float* __restrict__ bn_out,
    float* __restrict__ out)
{
    __shared__ float Lg[RS];   // 32 KB: g row; reused as h1 buffer
    __shared__ float Lh[RS];   // 32 KB: h0(=f) row

    const int t  = threadIdx.x;
    const int c4 = (t & 15) << 2;        // channels c4..c4+3 (16-lane clusters coalesce)
    const int w0 = (t >> 4) << 1;        // w pair (w0, w0+1)
    const int l  = t & 63;
    const int lm = (l & 48) | ((l + 15) & 15);   // channel-roll shuffles within 16-lane group
    const int lp = (l & 48) | ((l + 1)  & 15);

    // bijective XCD swizzle: 2048 blocks = 8 XCDs x 256 contiguous rows
    const int bid = blockIdx.x;
    const int bh  = ((bid & 7) << 8) | (bid >> 3);
    const int hrow = bh & (HH - 1);
    const long rowbase = (long)bh * RS;

    // clamped column offsets (valid addresses even at W edges)
    const long o0 = (long)w0 * CC + c4;
    const long o1 = o0 + CC;
    const long om = (long)((w0 > 0)      ? (w0 - 1) : 0)      * CC + c4;
    const long op = (long)((w0 < WW - 2) ? (w0 + 2) : (WW - 1)) * CC + c4;
    const bool zl = (w0 == 0);
    const bool zr = (w0 == WW - 2);

    // ---- phase 1a: conv (branch-free interior path) ----
    f4 acc[4][2];
    #pragma unroll
    for (int q = 0; q < 4; ++q) { acc[q][0] = (f4)0.f; acc[q][1] = (f4)0.f; }
    f4 fin0 = (f4)0.f, fin1 = (f4)0.f;
    const float* rowc = s0 + rowbase;

    if (hrow > 0 && hrow < HH - 1)
        conv3x3<true, true >(rowc, om, o0, o1, op, zl, zr, kg, kg1, kDx, kDy, c4, acc, fin0, fin1);
    else if (hrow == 0)
        conv3x3<false, true >(rowc, om, o0, o1, op, zl, zr, kg, kg1, kDx, kDy, c4, acc, fin0, fin1);
    else
        conv3x3<true, false>(rowc, om, o0, o1, op, zl, zr, kg, kg1, kDx, kDy, c4, acc, fin0, fin1);

    // ---- BN folds: y = S*x + B, optional positive scale folded in ----
    #define BNFOLD(P, S, B, SC) { \
        const f4 ga  = vload((P) + c4);        \
        const f4 be  = vload((P) + 64 + c4);   \
        const f4 mu  = vload((P) + 128 + c4);  \
        const f4 va  = vload((P) + 192 + c4);  \
        const f4 sc0 = ga * vrsq_eps(va);      \
        S = sc0 * (SC);                        \
        B = (be - mu * sc0) * (SC); }

    f4 s_g, b_g, s_g1, b_g1, s_dx, b_dx, s_dy, b_dy;
    BNFOLD(bng,  s_g,  b_g,  1.0f);
    BNFOLD(bng1, s_g1, b_g1, 1.0f);
    BNFOLD(bnDx, s_dx, b_dx, 0.4f);   // 2*DT folded: tbx = 2*Bx directly
    BNFOLD(bnDy, s_dy, b_dy, 0.4f);

    // ---- g, g1 + publish LDS rows ASAP ----
    f4 gq[2], g1q[2], hq[2];
    gq[0]  = vrelu(acc[0][0] * s_g  + b_g );
    gq[1]  = vrelu(acc[0][1] * s_g  + b_g );
    g1q[0] = vrelu(acc[1][0] * s_g1 + b_g1);
    g1q[1] = vrelu(acc[1][1] * s_g1 + b_g1);
    hq[0] = fin0; hq[1] = fin1;
    vstore(&Lg[(w0    ) * CC + c4], gq[0]);
    vstore(&Lg[(w0 + 1) * CC + c4], gq[1]);
    vstore(&Lh[(w0    ) * CC + c4], fin0);
    vstore(&Lh[(w0 + 1) * CC + c4], fin1);

    // ---- PDE coefficients (between store and barrier: overlaps other waves) ----
    f4 cWm[2], cWp[2], cCm[2], cCp[2], A0[2], PqD[2], vy[2];
    #pragma unroll
    for (int wi = 0; wi < 2; ++wi) {
        const f4 tbx = vrelu(acc[2][wi] * s_dx + b_dx);   // = 2*DT*Dx
        const f4 tby = vrelu(acc[3][wi] * s_dy + b_dy);   // = 2*DT*Dy
        // vy = 0.5*(g1[c-1] - g1[c+1]) wrap: in-quad + 2 shuffles
        const f4 g1v = g1q[wi];
        const float cm3 = __shfl(g1v.w, lm);
        const float cp0 = __shfl(g1v.x, lp);
        f4 cm, cp;
        cm.x = cm3;   cm.y = g1v.x; cm.z = g1v.y; cm.w = g1v.z;
        cp.x = g1v.y; cp.y = g1v.z; cp.z = g1v.w; cp.w = cp0;
        vy[wi] = 0.5f * (cm - cp);
        const f4 Dv = vrcp((f4)1.f + tbx + tby);
        const f4 Ax = gq[wi]  * 0.2f;
        const f4 Ay = g1q[wi] * 0.2f;
        cWm[wi] = Dv * (tbx - Ax);            // coeff of h[w-1]
        cWp[wi] = Dv * (tbx + Ax);            // coeff of h[w+1]
        cCm[wi] = Dv * (tby - Ay);            // coeff of h[c-1]
        cCp[wi] = Dv * (tby + Ay);            // coeff of h[c+1]
        A0[wi]  = Dv * hq[wi] * ((f4)1.4f - tbx - tby);   // h0==f both iters (K=2 lag)
        PqD[wi] = Dv * (-0.4f);               // cE = PqD*(ux+vy)
    }
    __syncthreads();   // barrier A: g,f visible

    // ---- phase 1b: cE from ux (W-neighbors of g wrap via LDS) ----
    f4 cE[2];
    #pragma unroll
    for (int wi = 0; wi < 2; ++wi) {
        const int w = w0 + wi;
        const f4 gm = vload(&Lg[((w - 1) & (WW - 1)) * CC + c4]);
        const f4 gp = vload(&Lg[((w + 1) & (WW - 1)) * CC + c4]);
        cE[wi] = PqD[wi] * ((f4)0.5f * (gm - gp) + vy[wi]);
    }

    // ---- PDE iter 1 (h = f, W-neighbors from Lh) ----
    f4 hn[2];
    #pragma unroll
    for (int wi = 0; wi < 2; ++wi) {
        const int w = w0 + wi;
        const f4 hm = vload(&Lh[((w - 1) & (WW - 1)) * CC + c4]);
        const f4 hp = vload(&Lh[((w + 1) & (WW - 1)) * CC + c4]);
        const f4 hv = hq[wi];
        const float m3 = __shfl(hv.w, lm);
        const float p0 = __shfl(hv.x, lp);
        f4 cm, cp;
        cm.x = m3;   cm.y = hv.x; cm.z = hv.y; cm.w = hv.z;
        cp.x = hv.y; cp.y = hv.z; cp.z = hv.w; cp.w = p0;
        hn[wi] = A0[wi] + cE[wi] * hv + cWm[wi] * hm + cWp[wi] * hp
               + cCm[wi] * cm + cCp[wi] * cp;
    }
    __syncthreads();   // barrier B: Lg(1b)/Lh(iter1) reads done
    vstore(&Lg[(w0    ) * CC + c4], hn[0]);   // Lg now holds h1
    vstore(&Lg[(w0 + 1) * CC + c4], hn[1]);
    hq[0] = hn[0]; hq[1] = hn[1];
    __syncthreads();   // barrier C: h1 visible

    // ---- PDE iter 2 (W-neighbors from Lg = h1) ----
    #pragma unroll
    for (int wi = 0; wi < 2; ++wi) {
        const int w = w0 + wi;
        const f4 hm = vload(&Lg[((w - 1) & (WW - 1)) * CC + c4]);
        const f4 hp = vload(&Lg[((w + 1) & (WW - 1)) * CC + c4]);
        const f4 hv = hq[wi];
        const float m3 = __shfl(hv.w, lm);
        const float p0 = __shfl(hv.x, lp);
        f4 cm, cp;
        cm.x = m3;   cm.y = hv.x; cm.z = hv.y; cm.w = hv.z;
        cp.x = hv.y; cp.y = hv.z; cp.z = hv.w; cp.w = p0;
        hn[wi] = A0[wi] + cE[wi] * hv + cWm[wi] * hm + cWp[wi] * hp
               + cCm[wi] * cm + cCp[wi] * cp;
    }

    // ---- epilogue: BN + ReLU, float4 store ----
    f4 s_o, b_o;
    BNFOLD(bn_out, s_o, b_o, 1.0f);
    #undef BNFOLD
    vstore(out + rowbase + o0, vrelu(hn[0] * s_o + b_o));
    vstore(out + rowbase + o1, vrelu(hn[1] * s_o + b_o));
}

extern "C" void kernel_launch(void* const* d_in, const int* in_sizes, int n_in,
                              void* d_out, int out_size, void* d_ws, size_t ws_size,
                              hipStream_t stream) {
    const float* s0   = (const float*)d_in[0];
    const float* kg   = (const float*)d_in[1];
    const float* kg1  = (const float*)d_in[2];
    const float* kDx  = (const float*)d_in[3];
    const float* kDy  = (const float*)d_in[4];
    const float* bng  = (const float*)d_in[5];
    const float* bng1 = (const float*)d_in[6];
    const float* bnDx = (const float*)d_in[7];
    const float* bnDy = (const float*)d_in[8];
    const float* bno  = (const float*)d_in[9];
    float* out = (float*)d_out;

    dim3 grid(16 * 128);   // one block per (batch, row), XCD-swizzled in-kernel
    dim3 block(BS);
    diffusion_fused<<<grid, block, 0, stream>>>(
        s0, kg, kg1, kDx, kDy, bng, bng1, bnDx, bnDy, bno, out);
}

// Round 4
// 198.017 us; speedup vs baseline: 2.7637x; 1.1364x over previous
//
#include <hip/hip_runtime.h>

#define HH 128
#define WW 128
#define CC 64
#define BS 1024
#define RS (WW * CC)    // row stride in floats

typedef float f4 __attribute__((ext_vector_type(4)));

static __device__ __forceinline__ f4 vload(const float* __restrict__ p) {
    return *reinterpret_cast<const f4*>(p);
}
static __device__ __forceinline__ void vstore(float* p, f4 v) {
    *reinterpret_cast<f4*>(p) = v;
}
static __device__ __forceinline__ f4 vrelu(f4 a) {
    f4 r;
    #pragma unroll
    for (int i = 0; i < 4; ++i) r[i] = fmaxf(a[i], 0.f);
    return r;
}
static __device__ __forceinline__ f4 vrsq_eps(f4 a) {   // 1/sqrt(a+eps), HW v_rsq_f32
    f4 r;
    #pragma unroll
    for (int i = 0; i < 4; ++i) r[i] = __builtin_amdgcn_rsqf(a[i] + 1e-3f);
    return r;
}
static __device__ __forceinline__ f4 vrcp(f4 a) {       // 1/a, HW v_rcp_f32
    f4 r;
    #pragma unroll
    for (int i = 0; i < 4; ++i) r[i] = __builtin_amdgcn_rcpf(a[i]);
    return r;
}
static __device__ __forceinline__ f4 shfl4(f4 v, int lane) {
    f4 r;
    r.x = __shfl(v.x, lane);
    r.y = __shfl(v.y, lane);
    r.z = __shfl(v.z, lane);
    r.w = __shfl(v.w, lane);
    return r;
}

// NOTE: no waves-per-EU pin (round 2: pin -> 32-VGPR target -> 1.5 GB spill).
// NOTE: 1024-thr block @ 2 blocks/CU pins the budget at exactly 64 VGPR; every
// change must be liveness-neutral vs the round-1 shape (round 3: +pressure -> spill).
__global__ __launch_bounds__(BS) void diffusion_fused(
    const float* __restrict__ s0,
    const float* __restrict__ kg,  const float* __restrict__ kg1,
    const float* __restrict__ kDx, const float* __restrict__ kDy,
    const float* __restrict__ bng,  const float* __restrict__ bng1,
    const float* __restrict__ bnDx, const float* __restrict__ bnDy,
    const float* __restrict__ bn_out,
    float* __restrict__ out)
{
    __shared__ float Lg[RS];              // 32 KB: g row (ux W-neighbors)
    __shared__ float Fhalo[2 * 16 * CC];  // 8 KB: f wave-boundary cols [side][wave][c]
    __shared__ float Hhalo[2 * 16 * CC];  // 8 KB: h1 wave-boundary cols

    const int t  = threadIdx.x;
    const int c4 = (t & 15) << 2;        // channels c4..c4+3
    const int w0 = (t >> 4) << 1;        // w pair (w0, w0+1)
    const int l  = t & 63;
    const int jg = l >> 4;               // pair slot within wave: 0..3
    const int kw = t >> 6;               // wave id: 0..15 (wave owns w in [8kw, 8kw+8))
    const int lm = (l & 48) | ((l + 15) & 15);   // channel-roll shuffles (16-lane groups)
    const int lp = (l & 48) | ((l + 1)  & 15);

    // bijective XCD swizzle: 2048 blocks = 8 XCDs x 256 contiguous rows
    const int bid = blockIdx.x;
    const int bh  = ((bid & 7) << 8) | (bid >> 3);
    const int hrow = bh & (HH - 1);
    const long rowbase = (long)bh * RS;

    // ---- phase 1a: 3x3 depthwise conv (SAME, zero pad) — round-1 shape ----
    f4 acc[4][2];
    #pragma unroll
    for (int q = 0; q < 4; ++q) { acc[q][0] = (f4)0.f; acc[q][1] = (f4)0.f; }
    f4 fin0 = (f4)0.f, fin1 = (f4)0.f;

    const float* wptr[4] = { kg, kg1, kDx, kDy };

    #pragma unroll
    for (int dh = -1; dh <= 1; ++dh) {
        const int h2 = hrow + dh;
        if (h2 < 0 || h2 >= HH) continue;          // block-uniform branch
        const float* rp = s0 + rowbase + (long)dh * RS;
        f4 in[4];                                  // columns w0-1 .. w0+2
        #pragma unroll
        for (int jj = 0; jj < 4; ++jj) {
            const int wc = w0 - 1 + jj;
            if (wc >= 0 && wc < WW) in[jj] = vload(rp + wc * CC + c4);
            else                    in[jj] = (f4)0.f;   // zero pad
        }
        if (dh == 0) { fin0 = in[1]; fin1 = in[2]; }
        #pragma unroll
        for (int dw = 0; dw < 3; ++dw) {
            const int kk = (dh + 1) * 3 + dw;
            #pragma unroll
            for (int q = 0; q < 4; ++q) {
                const f4 wq = vload(wptr[q] + kk * CC + c4);
                acc[q][0] += in[dw]     * wq;
                acc[q][1] += in[dw + 1] * wq;
            }
        }
    }

    // ---- BN folds: y = S*x + B, optional positive scale folded ----
    #define BNFOLD(P, S, B, SC) { \
        const f4 ga  = vload((P) + c4);        \
        const f4 be  = vload((P) + 64 + c4);   \
        const f4 mu  = vload((P) + 128 + c4);  \
        const f4 va  = vload((P) + 192 + c4);  \
        const f4 sc0 = ga * vrsq_eps(va);      \
        S = sc0 * (SC);                        \
        B = (be - mu * sc0) * (SC); }

    f4 s_g, b_g, s_g1, b_g1, s_dx, b_dx, s_dy, b_dy;
    BNFOLD(bng,  s_g,  b_g,  1.0f);
    BNFOLD(bng1, s_g1, b_g1, 1.0f);
    BNFOLD(bnDx, s_dx, b_dx, 0.4f);   // 2*DT folded: tbx = 2*Bx directly
    BNFOLD(bnDy, s_dy, b_dy, 0.4f);

    f4 gq[2], g1q[2], hq[2];
    gq[0]  = vrelu(acc[0][0] * s_g  + b_g );
    gq[1]  = vrelu(acc[0][1] * s_g  + b_g );
    g1q[0] = vrelu(acc[1][0] * s_g1 + b_g1);
    g1q[1] = vrelu(acc[1][1] * s_g1 + b_g1);
    hq[0] = fin0; hq[1] = fin1;

    // publish g full row (ux needs cross-thread W-neighbors) + f wave-boundary halos
    vstore(&Lg[(w0    ) * CC + c4], gq[0]);
    vstore(&Lg[(w0 + 1) * CC + c4], gq[1]);
    if (jg == 0) vstore(&Fhalo[kw * CC + c4], fin0);              // first col w=8kw
    if (jg == 3) vstore(&Fhalo[(16 + kw) * CC + c4], fin1);       // last col  w=8kw+7

    // ---- PDE coefficients (pre-barrier; same liveness as round 1) ----
    f4 cWm[2], cWp[2], cCm[2], cCp[2], A0[2], PqD[2], vy[2];
    #pragma unroll
    for (int wi = 0; wi < 2; ++wi) {
        const f4 tbx = vrelu(acc[2][wi] * s_dx + b_dx);   // = 2*DT*Dx
        const f4 tby = vrelu(acc[3][wi] * s_dy + b_dy);   // = 2*DT*Dy
        // vy = 0.5*(g1[c-1] - g1[c+1]) wrap: in-quad + 2 shuffles
        const f4 g1v = g1q[wi];
        const float cm3 = __shfl(g1v.w, lm);
        const float cp0 = __shfl(g1v.x, lp);
        f4 cm, cp;
        cm.x = cm3;   cm.y = g1v.x; cm.z = g1v.y; cm.w = g1v.z;
        cp.x = g1v.y; cp.y = g1v.z; cp.z = g1v.w; cp.w = cp0;
        vy[wi] = 0.5f * (cm - cp);
        const f4 Dv = vrcp((f4)1.f + tbx + tby);
        const f4 Ax = gq[wi]  * 0.2f;
        const f4 Ay = g1q[wi] * 0.2f;
        cWm[wi] = Dv * (tbx - Ax);            // coeff of h[w-1]
        cWp[wi] = Dv * (tbx + Ax);            // coeff of h[w+1]
        cCm[wi] = Dv * (tby - Ay);            // coeff of h[c-1]
        cCp[wi] = Dv * (tby + Ay);            // coeff of h[c+1]
        A0[wi]  = Dv * hq[wi] * ((f4)1.4f - tbx - tby);   // h0==f both iters (K=2 lag)
        PqD[wi] = Dv * (-0.4f);               // cE = PqD*(ux+vy)
    }
    __syncthreads();   // barrier A: Lg + Fhalo visible

    // ---- phase 1b: cE from ux (W-neighbors of g wrap via LDS, as round 1) ----
    f4 cE[2];
    #pragma unroll
    for (int wi = 0; wi < 2; ++wi) {
        const int w = w0 + wi;
        const f4 gm = vload(&Lg[((w - 1) & (WW - 1)) * CC + c4]);
        const f4 gp = vload(&Lg[((w + 1) & (WW - 1)) * CC + c4]);
        cE[wi] = PqD[wi] * ((f4)0.5f * (gm - gp) + vy[wi]);
    }

    // ---- PDE iter 1 (h = f): W-neighbors via shfl(lane+-16) + wave-boundary halo ----
    f4 hlm = shfl4(hq[1], (l - 16) & 63);    // f[w0-1]  (valid for jg>0)
    f4 hrp = shfl4(hq[0], (l + 16) & 63);    // f[w0+2]  (valid for jg<3)
    if (jg == 0) hlm = vload(&Fhalo[(16 + ((kw + 15) & 15)) * CC + c4]);  // wave kw-1 last
    if (jg == 3) hrp = vload(&Fhalo[((kw + 1) & 15) * CC + c4]);          // wave kw+1 first

    f4 hn0, hn1;
    {
        const f4 hv = hq[0];
        const float m3 = __shfl(hv.w, lm);
        const float p0 = __shfl(hv.x, lp);
        f4 cm, cp;
        cm.x = m3;   cm.y = hv.x; cm.z = hv.y; cm.w = hv.z;
        cp.x = hv.y; cp.y = hv.z; cp.z = hv.w; cp.w = p0;
        hn0 = A0[0] + cE[0] * hv + cWm[0] * hlm + cWp[0] * hq[1]
            + cCm[0] * cm + cCp[0] * cp;
    }
    {
        const f4 hv = hq[1];
        const float m3 = __shfl(hv.w, lm);
        const float p0 = __shfl(hv.x, lp);
        f4 cm, cp;
        cm.x = m3;   cm.y = hv.x; cm.z = hv.y; cm.w = hv.z;
        cp.x = hv.y; cp.y = hv.z; cp.z = hv.w; cp.w = p0;
        hn1 = A0[1] + cE[1] * hv + cWm[1] * hq[0] + cWp[1] * hrp
            + cCm[1] * cm + cCp[1] * cp;
    }

    // publish h1 wave-boundary halos
    if (jg == 0) vstore(&Hhalo[kw * CC + c4], hn0);
    if (jg == 3) vstore(&Hhalo[(16 + kw) * CC + c4], hn1);
    __syncthreads();   // barrier B: Hhalo visible (only barrier between iters)

    // ---- PDE iter 2: same exchange pattern on h1 ----
    f4 hlm2 = shfl4(hn1, (l - 16) & 63);
    f4 hrp2 = shfl4(hn0, (l + 16) & 63);
    if (jg == 0) hlm2 = vload(&Hhalo[(16 + ((kw + 15) & 15)) * CC + c4]);
    if (jg == 3) hrp2 = vload(&Hhalo[((kw + 1) & 15) * CC + c4]);

    f4 h20, h21;
    {
        const f4 hv = hn0;
        const float m3 = __shfl(hv.w, lm);
        const float p0 = __shfl(hv.x, lp);
        f4 cm, cp;
        cm.x = m3;   cm.y = hv.x; cm.z = hv.y; cm.w = hv.z;
        cp.x = hv.y; cp.y = hv.z; cp.z = hv.w; cp.w = p0;
        h20 = A0[0] + cE[0] * hv + cWm[0] * hlm2 + cWp[0] * hn1
            + cCm[0] * cm + cCp[0] * cp;
    }
    {
        const f4 hv = hn1;
        const float m3 = __shfl(hv.w, lm);
        const float p0 = __shfl(hv.x, lp);
        f4 cm, cp;
        cm.x = m3;   cm.y = hv.x; cm.z = hv.y; cm.w = hv.z;
        cp.x = hv.y; cp.y = hv.z; cp.z = hv.w; cp.w = p0;
        h21 = A0[1] + cE[1] * hv + cWm[1] * hn0 + cWp[1] * hrp2
            + cCm[1] * cm + cCp[1] * cp;
    }

    // ---- epilogue: BN + ReLU, float4 store ----
    f4 s_o, b_o;
    BNFOLD(bn_out, s_o, b_o, 1.0f);
    #undef BNFOLD
    vstore(out + rowbase + (long)w0 * CC + c4,       vrelu(h20 * s_o + b_o));
    vstore(out + rowbase + (long)(w0 + 1) * CC + c4, vrelu(h21 * s_o + b_o));
}

extern "C" void kernel_launch(void* const* d_in, const int* in_sizes, int n_in,
                              void* d_out, int out_size, void* d_ws, size_t ws_size,
                              hipStream_t stream) {
    const float* s0   = (const float*)d_in[0];
    const float* kg   = (const float*)d_in[1];
    const float* kg1  = (const float*)d_in[2];
    const float* kDx  = (const float*)d_in[3];
    const float* kDy  = (const float*)d_in[4];
    const float* bng  = (const float*)d_in[5];
    const float* bng1 = (const float*)d_in[6];
    const float* bnDx = (const float*)d_in[7];
    const float* bnDy = (const float*)d_in[8];
    const float* bno  = (const float*)d_in[9];
    float* out = (float*)d_out;

    dim3 grid(16 * 128);   // one block per (batch, row), XCD-swizzled in-kernel
    dim3 block(BS);
    diffusion_fused<<<grid, block, 0, stream>>>(
        s0, kg, kg1, kDx, kDy, bng, bng1, bnDx, bnDy, bno, out);
}

// Round 5
// 176.677 us; speedup vs baseline: 3.0975x; 1.1208x over previous
//
#include <hip/hip_runtime.h>

#define HH 128
#define WW 128
#define CC 64
#define BS 512
#define RS (WW * CC)    // row stride in floats
#define NPT 4           // contiguous w-points per thread
#define NSTRIP 32       // strips per row (NSTRIP * NPT == WW)

typedef float f4 __attribute__((ext_vector_type(4)));

static __device__ __forceinline__ f4 vload(const float* __restrict__ p) {
    return *reinterpret_cast<const f4*>(p);
}
static __device__ __forceinline__ void vstore(float* p, f4 v) {
    *reinterpret_cast<f4*>(p) = v;
}
static __device__ __forceinline__ f4 vrelu(f4 a) {
    f4 r;
    #pragma unroll
    for (int i = 0; i < 4; ++i) r[i] = fmaxf(a[i], 0.f);
    return r;
}
static __device__ __forceinline__ f4 vrsq_eps(f4 a) {   // 1/sqrt(a+eps), HW v_rsq_f32
    f4 r;
    #pragma unroll
    for (int i = 0; i < 4; ++i) r[i] = __builtin_amdgcn_rsqf(a[i] + 1e-3f);
    return r;
}
static __device__ __forceinline__ f4 vrcp(f4 a) {       // 1/a, HW v_rcp_f32
    f4 r;
    #pragma unroll
    for (int i = 0; i < 4; ++i) r[i] = __builtin_amdgcn_rcpf(a[i]);
    return r;
}

// Channel-roll (c+-1 wrap over 64 ch) of an f4 held across a 16-lane cq group.
static __device__ __forceinline__ void croll(f4 v, int lm, int lp, f4& cm, f4& cp) {
    const float m3 = __shfl(v.w, lm);
    const float p0 = __shfl(v.x, lp);
    cm.x = m3;  cm.y = v.x; cm.z = v.y; cm.w = v.z;
    cp.x = v.y; cp.y = v.z; cp.z = v.w; cp.w = p0;
}

// NOTE (r2): never pin min-waves-per-EU -> allocator spills catastrophically.
// NOTE (r4): barrier/LDS machinery is NOT the bottleneck; conv VMEM latency is.
// Block 512 = 8 waves: allocator free up to 256 VGPR, spill-free by construction.
__global__ __launch_bounds__(BS) void diffusion_fused(
    const float* __restrict__ s0,
    const float* __restrict__ kg,  const float* __restrict__ kg1,
    const float* __restrict__ kDx, const float* __restrict__ kDy,
    const float* __restrict__ bng,  const float* __restrict__ bng1,
    const float* __restrict__ bnDx, const float* __restrict__ bnDy,
    const float* __restrict__ bn_out,
    float* __restrict__ out)
{
    // Halo rings: [side(0=strip point0,1=strip point3)][strip][channel], 16 KB each.
    __shared__ float GH[2 * NSTRIP * CC];   // g edges (for ux wrap)
    __shared__ float FH[2 * NSTRIP * CC];   // f edges (iter-1 W-neighbors)
    __shared__ float HHb[2 * NSTRIP * CC];  // h1 edges (iter-2 W-neighbors)

    const int t  = threadIdx.x;
    const int cq = t & 15;
    const int c4 = cq << 2;              // channels c4..c4+3
    const int s  = t >> 4;               // strip 0..31
    const int w0 = s << 2;               // output columns w0..w0+3
    const int l  = t & 63;
    const int lm = (l & 48) | ((l + 15) & 15);   // channel-roll shuffle lanes
    const int lp = (l & 48) | ((l + 1)  & 15);
    const int sl = (s + NSTRIP - 1) & (NSTRIP - 1);  // strip to the left (wrap)
    const int sr = (s + 1) & (NSTRIP - 1);           // strip to the right (wrap)

    // bijective XCD swizzle: 2048 blocks = 8 XCDs x 256 contiguous rows
    const int bid = blockIdx.x;
    const int bh  = ((bid & 7) << 8) | (bid >> 3);
    const int hrow = bh & (HH - 1);
    const long rowbase = (long)bh * RS;

    // column byte offsets for the 6-column input window w0-1 .. w0+4 (clamped)
    const bool zl = (s == 0), zr = (s == NSTRIP - 1);
    int oc[6];
    oc[0] = (zl ? 0 : (w0 - 1)) * CC + c4;
    #pragma unroll
    for (int j = 1; j <= 4; ++j) oc[j] = (w0 + j - 1) * CC + c4;
    oc[5] = (zr ? (WW - 1) : (w0 + 4)) * CC + c4;

    // ---- phase 1: 3x3 depthwise conv, 4 kernels x 4 points ----
    f4 acc[4][NPT];
    #pragma unroll
    for (int q = 0; q < 4; ++q)
        #pragma unroll
        for (int i = 0; i < NPT; ++i) acc[q][i] = (f4)0.f;

    const float* wptr[4] = { kg, kg1, kDx, kDy };

    #pragma unroll
    for (int dh = -1; dh <= 1; ++dh) {
        const int h2 = hrow + dh;
        if (h2 < 0 || h2 >= HH) continue;        // block-uniform branch
        const float* rp = s0 + rowbase + (long)dh * RS;
        f4 in[6];
        #pragma unroll
        for (int j = 0; j < 6; ++j) in[j] = vload(rp + oc[j]);
        if (zl) in[0] = (f4)0.f;                 // zero pad (cndmask)
        if (zr) in[5] = (f4)0.f;
        #pragma unroll
        for (int dw = 0; dw < 3; ++dw) {
            const int kk = (dh + 1) * 3 + dw;
            #pragma unroll
            for (int q = 0; q < 4; ++q) {
                const f4 wq = vload(wptr[q] + kk * CC + c4);   // 1 load : 16 FMAs
                #pragma unroll
                for (int i = 0; i < NPT; ++i) acc[q][i] += in[dw + i] * wq;
            }
        }
    }

    // ---- BN folds: y = S*x + B (2*DT folded into Dx/Dy) ----
    #define BNFOLD(P, S, B, SC) { \
        const f4 ga  = vload((P) + c4);        \
        const f4 be  = vload((P) + 64 + c4);   \
        const f4 mu  = vload((P) + 128 + c4);  \
        const f4 va  = vload((P) + 192 + c4);  \
        const f4 sc0 = ga * vrsq_eps(va);      \
        S = sc0 * (SC);                        \
        B = (be - mu * sc0) * (SC); }

    f4 s_g, b_g, s_g1, b_g1, s_dx, b_dx, s_dy, b_dy;
    BNFOLD(bng,  s_g,  b_g,  1.0f);
    BNFOLD(bng1, s_g1, b_g1, 1.0f);
    BNFOLD(bnDx, s_dx, b_dx, 0.4f);
    BNFOLD(bnDy, s_dy, b_dy, 0.4f);

    // f (= initial h): reload center row, L1-hot from the conv pass
    f4 h[NPT];
    {
        const float* rc = s0 + rowbase;
        #pragma unroll
        for (int i = 0; i < NPT; ++i) h[i] = vload(rc + oc[i + 1]);
    }

    // g, g1; publish g/f strip-edge halos
    f4 g[NPT], g1[NPT];
    #pragma unroll
    for (int i = 0; i < NPT; ++i) {
        g[i]  = vrelu(acc[0][i] * s_g  + b_g );
        g1[i] = vrelu(acc[1][i] * s_g1 + b_g1);
    }
    vstore(&GH[s * CC + c4],              g[0]);
    vstore(&GH[(NSTRIP + s) * CC + c4],   g[NPT - 1]);
    vstore(&FH[s * CC + c4],              h[0]);
    vstore(&FH[(NSTRIP + s) * CC + c4],   h[NPT - 1]);

    // per-point coefficients (g,g1 die here except edge fixup parts)
    f4 cWm[NPT], cWp[NPT], cCm[NPT], cCp[NPT], A0[NPT], PqD[NPT], uv[NPT];
    #pragma unroll
    for (int i = 0; i < NPT; ++i) {
        const f4 tbx = vrelu(acc[2][i] * s_dx + b_dx);   // = 2*DT*Dx
        const f4 tby = vrelu(acc[3][i] * s_dy + b_dy);   // = 2*DT*Dy
        const f4 Dv  = vrcp((f4)1.f + tbx + tby);
        const f4 Ax  = g[i]  * 0.2f;
        const f4 Ay  = g1[i] * 0.2f;
        cWm[i] = Dv * (tbx - Ax);
        cWp[i] = Dv * (tbx + Ax);
        cCm[i] = Dv * (tby - Ay);
        cCp[i] = Dv * (tby + Ay);
        A0[i]  = Dv * h[i] * ((f4)1.4f - tbx - tby);   // h0 == f both iters (K=2 lag)
        PqD[i] = Dv * (-0.4f);
        // vy = 0.5*(g1[c-1]-g1[c+1]); interior ux parts from register g
        f4 cm, cp;
        croll(g1[i], lm, lp, cm, cp);
        uv[i] = 0.5f * (cm - cp);
    }
    uv[0] -= 0.5f * g[1];                 // ux[0] = 0.5*(gL - g[1]); gL after barrier
    uv[1] += 0.5f * (g[0] - g[2]);
    uv[2] += 0.5f * (g[1] - g[3]);
    uv[3] += 0.5f * g[2];                 // ux[3] = 0.5*(g[2] - gR)
    __syncthreads();   // barrier A: GH, FH visible

    // ---- cE from ux edges ----
    f4 cE[NPT];
    {
        const f4 gL = vload(&GH[(NSTRIP + sl) * CC + c4]);  // g[w0-1] (wrap)
        const f4 gR = vload(&GH[sr * CC + c4]);             // g[w0+4] (wrap)
        cE[0] = PqD[0] * (uv[0] + 0.5f * gL);
        cE[1] = PqD[1] * uv[1];
        cE[2] = PqD[2] * uv[2];
        cE[3] = PqD[3] * (uv[3] - 0.5f * gR);
    }

    // ---- PDE iter 1 (h == f): interior W-neighbors in registers ----
    f4 hn[NPT];
    {
        const f4 hL = vload(&FH[(NSTRIP + sl) * CC + c4]);
        const f4 hR = vload(&FH[sr * CC + c4]);
        #pragma unroll
        for (int i = 0; i < NPT; ++i) {
            const f4 hm = (i == 0)       ? hL : h[i - 1];
            const f4 hp = (i == NPT - 1) ? hR : h[i + 1];
            f4 cm, cp;
            croll(h[i], lm, lp, cm, cp);
            hn[i] = A0[i] + cE[i] * h[i] + cWm[i] * hm + cWp[i] * hp
                  + cCm[i] * cm + cCp[i] * cp;
        }
    }
    vstore(&HHb[s * CC + c4],            hn[0]);
    vstore(&HHb[(NSTRIP + s) * CC + c4], hn[NPT - 1]);
    __syncthreads();   // barrier B: h1 edges visible

    // ---- PDE iter 2 ----
    f4 h2v[NPT];
    {
        const f4 hL = vload(&HHb[(NSTRIP + sl) * CC + c4]);
        const f4 hR = vload(&HHb[sr * CC + c4]);
        #pragma unroll
        for (int i = 0; i < NPT; ++i) {
            const f4 hm = (i == 0)       ? hL : hn[i - 1];
            const f4 hp = (i == NPT - 1) ? hR : hn[i + 1];
            f4 cm, cp;
            croll(hn[i], lm, lp, cm, cp);
            h2v[i] = A0[i] + cE[i] * hn[i] + cWm[i] * hm + cWp[i] * hp
                   + cCm[i] * cm + cCp[i] * cp;
        }
    }

    // ---- epilogue: BN + ReLU ----
    f4 s_o, b_o;
    BNFOLD(bn_out, s_o, b_o, 1.0f);
    #undef BNFOLD
    #pragma unroll
    for (int i = 0; i < NPT; ++i)
        vstore(out + rowbase + oc[i + 1], vrelu(h2v[i] * s_o + b_o));
}

extern "C" void kernel_launch(void* const* d_in, const int* in_sizes, int n_in,
                              void* d_out, int out_size, void* d_ws, size_t ws_size,
                              hipStream_t stream) {
    const float* s0   = (const float*)d_in[0];
    const float* kg   = (const float*)d_in[1];
    const float* kg1  = (const float*)d_in[2];
    const float* kDx  = (const float*)d_in[3];
    const float* kDy  = (const float*)d_in[4];
    const float* bng  = (const float*)d_in[5];
    const float* bng1 = (const float*)d_in[6];
    const float* bnDx = (const float*)d_in[7];
    const float* bnDy = (const float*)d_in[8];
    const float* bno  = (const float*)d_in[9];
    float* out = (float*)d_out;

    dim3 grid(16 * 128);   // one block per (batch, row), XCD-swizzled in-kernel
    dim3 block(BS);
    diffusion_fused<<<grid, block, 0, stream>>>(
        s0, kg, kg1, kDx, kDy, bng, bng1, bnDx, bnDy, bno, out);
}

// Round 6
// 171.347 us; speedup vs baseline: 3.1939x; 1.0311x over previous
//
#include <hip/hip_runtime.h>

#define HH 128
#define WW 128
#define CC 64
#define BS 512
#define RS (WW * CC)    // row stride in floats
#define NPT 4           // contiguous w-points per thread
#define NSTRIP 32       // strips per row (NSTRIP * NPT == WW)

typedef float f4 __attribute__((ext_vector_type(4)));

static __device__ __forceinline__ f4 vload(const float* __restrict__ p) {
    return *reinterpret_cast<const f4*>(p);
}
static __device__ __forceinline__ void vstore(float* p, f4 v) {
    *reinterpret_cast<f4*>(p) = v;
}
static __device__ __forceinline__ f4 vrelu(f4 a) {
    f4 r;
    #pragma unroll
    for (int i = 0; i < 4; ++i) r[i] = fmaxf(a[i], 0.f);
    return r;
}
static __device__ __forceinline__ f4 vrsq_eps(f4 a) {   // 1/sqrt(a+eps), HW v_rsq_f32
    f4 r;
    #pragma unroll
    for (int i = 0; i < 4; ++i) r[i] = __builtin_amdgcn_rsqf(a[i] + 1e-3f);
    return r;
}
static __device__ __forceinline__ f4 vrcp(f4 a) {       // 1/a, HW v_rcp_f32
    f4 r;
    #pragma unroll
    for (int i = 0; i < 4; ++i) r[i] = __builtin_amdgcn_rcpf(a[i]);
    return r;
}

// Channel-roll (c+-1 wrap over 64 ch) of an f4 held across a 16-lane cq group.
static __device__ __forceinline__ void croll(f4 v, int lm, int lp, f4& cm, f4& cp) {
    const float m3 = __shfl(v.w, lm);
    const float p0 = __shfl(v.x, lp);
    cm.x = m3;  cm.y = v.x; cm.z = v.y; cm.w = v.z;
    cp.x = v.y; cp.y = v.z; cp.z = v.w; cp.w = p0;
}

// NOTE (r2): never pin min-waves-per-EU -> allocator spills catastrophically.
// NOTE (r4): barrier/LDS machinery is NOT the bottleneck; conv VMEM latency is.
// NOTE (r5): NPT=4 strips halved per-output VMEM: 103 -> 70 us at 92 VGPR.
// This round: two-pass conv (g,g1 then Dx,Dy) halves accumulator liveness so
// more loads fit in flight. VGPR must stay <= 128 (occupancy bucket edge, m69).
__global__ __launch_bounds__(BS) void diffusion_fused(
    const float* __restrict__ s0,
    const float* __restrict__ kg,  const float* __restrict__ kg1,
    const float* __restrict__ kDx, const float* __restrict__ kDy,
    const float* __restrict__ bng,  const float* __restrict__ bng1,
    const float* __restrict__ bnDx, const float* __restrict__ bnDy,
    const float* __restrict__ bn_out,
    float* __restrict__ out)
{
    // Halo rings: [side(0=strip point0,1=strip point3)][strip][channel], 16 KB each.
    __shared__ float GH[2 * NSTRIP * CC];   // g edges (for ux wrap)
    __shared__ float FH[2 * NSTRIP * CC];   // f edges (iter-1 W-neighbors)
    __shared__ float HHb[2 * NSTRIP * CC];  // h1 edges (iter-2 W-neighbors)

    const int t  = threadIdx.x;
    const int cq = t & 15;
    const int c4 = cq << 2;              // channels c4..c4+3
    const int s  = t >> 4;               // strip 0..31
    const int w0 = s << 2;               // output columns w0..w0+3
    const int l  = t & 63;
    const int lm = (l & 48) | ((l + 15) & 15);   // channel-roll shuffle lanes
    const int lp = (l & 48) | ((l + 1)  & 15);
    const int sl = (s + NSTRIP - 1) & (NSTRIP - 1);  // strip to the left (wrap)
    const int sr = (s + 1) & (NSTRIP - 1);           // strip to the right (wrap)

    // bijective XCD swizzle: 2048 blocks = 8 XCDs x 256 contiguous rows
    const int bid = blockIdx.x;
    const int bh  = ((bid & 7) << 8) | (bid >> 3);
    const int hrow = bh & (HH - 1);
    const long rowbase = (long)bh * RS;
    const bool rowm = (hrow > 0), rowp = (hrow < HH - 1);

    // column offsets for the 6-column input window w0-1 .. w0+4 (clamped)
    const bool zl = (s == 0), zr = (s == NSTRIP - 1);
    int oc[6];
    oc[0] = (zl ? 0 : (w0 - 1)) * CC + c4;
    #pragma unroll
    for (int j = 1; j <= 4; ++j) oc[j] = (w0 + j - 1) * CC + c4;
    oc[5] = (zr ? (WW - 1) : (w0 + 4)) * CC + c4;

    #define BNFOLD(P, S, B, SC) { \
        const f4 ga  = vload((P) + c4);        \
        const f4 be  = vload((P) + 64 + c4);   \
        const f4 mu  = vload((P) + 128 + c4);  \
        const f4 va  = vload((P) + 192 + c4);  \
        const f4 sc0 = ga * vrsq_eps(va);      \
        S = sc0 * (SC);                        \
        B = (be - mu * sc0) * (SC); }

    // ---- pass A: 3x3 depthwise conv for g, g1 (8 f4 accumulators only) ----
    f4 s_g, b_g, s_g1, b_g1;
    BNFOLD(bng,  s_g,  b_g,  1.0f);      // loads overlap pass-A compute
    BNFOLD(bng1, s_g1, b_g1, 1.0f);

    f4 ag[NPT], ag1[NPT];
    #pragma unroll
    for (int i = 0; i < NPT; ++i) { ag[i] = (f4)0.f; ag1[i] = (f4)0.f; }

    #pragma unroll
    for (int dh = -1; dh <= 1; ++dh) {
        if (dh == -1 && !rowm) continue;     // block-uniform
        if (dh ==  1 && !rowp) continue;
        const float* rp = s0 + rowbase + (long)dh * RS;
        f4 in[6];
        #pragma unroll
        for (int j = 0; j < 6; ++j) in[j] = vload(rp + oc[j]);
        if (zl) in[0] = (f4)0.f;
        if (zr) in[5] = (f4)0.f;
        #pragma unroll
        for (int dw = 0; dw < 3; ++dw) {
            const int kk = (dh + 1) * 3 + dw;
            const f4 wg  = vload(kg  + kk * CC + c4);
            const f4 wg1 = vload(kg1 + kk * CC + c4);
            #pragma unroll
            for (int i = 0; i < NPT; ++i) {
                ag[i]  += in[dw + i] * wg;
                ag1[i] += in[dw + i] * wg1;
            }
        }
    }

    f4 g[NPT], g1[NPT];
    #pragma unroll
    for (int i = 0; i < NPT; ++i) {
        g[i]  = vrelu(ag[i]  * s_g  + b_g );
        g1[i] = vrelu(ag1[i] * s_g1 + b_g1);
    }
    vstore(&GH[s * CC + c4],            g[0]);
    vstore(&GH[(NSTRIP + s) * CC + c4], g[NPT - 1]);

    // ---- pass B: conv for Dx, Dy (inputs now L1/L2-hot) + grab f ----
    f4 s_dx, b_dx, s_dy, b_dy;
    BNFOLD(bnDx, s_dx, b_dx, 0.4f);      // 2*DT folded: tbx = 2*Bx directly
    BNFOLD(bnDy, s_dy, b_dy, 0.4f);

    f4 adx[NPT], ady[NPT], h[NPT];
    #pragma unroll
    for (int i = 0; i < NPT; ++i) { adx[i] = (f4)0.f; ady[i] = (f4)0.f; }

    #pragma unroll
    for (int dh = -1; dh <= 1; ++dh) {
        if (dh == -1 && !rowm) continue;
        if (dh ==  1 && !rowp) continue;
        const float* rp = s0 + rowbase + (long)dh * RS;
        f4 in[6];
        #pragma unroll
        for (int j = 0; j < 6; ++j) in[j] = vload(rp + oc[j]);
        if (zl) in[0] = (f4)0.f;
        if (zr) in[5] = (f4)0.f;
        if (dh == 0) {
            #pragma unroll
            for (int i = 0; i < NPT; ++i) h[i] = in[i + 1];   // f
        }
        #pragma unroll
        for (int dw = 0; dw < 3; ++dw) {
            const int kk = (dh + 1) * 3 + dw;
            const f4 wdx = vload(kDx + kk * CC + c4);
            const f4 wdy = vload(kDy + kk * CC + c4);
            #pragma unroll
            for (int i = 0; i < NPT; ++i) {
                adx[i] += in[dw + i] * wdx;
                ady[i] += in[dw + i] * wdy;
            }
        }
    }
    vstore(&FH[s * CC + c4],            h[0]);
    vstore(&FH[(NSTRIP + s) * CC + c4], h[NPT - 1]);

    // ---- per-point PDE coefficients ----
    f4 cWm[NPT], cWp[NPT], cCm[NPT], cCp[NPT], A0[NPT], PqD[NPT], uv[NPT];
    #pragma unroll
    for (int i = 0; i < NPT; ++i) {
        const f4 tbx = vrelu(adx[i] * s_dx + b_dx);   // = 2*DT*Dx
        const f4 tby = vrelu(ady[i] * s_dy + b_dy);   // = 2*DT*Dy
        const f4 Dv  = vrcp((f4)1.f + tbx + tby);
        const f4 Ax  = g[i]  * 0.2f;
        const f4 Ay  = g1[i] * 0.2f;
        cWm[i] = Dv * (tbx - Ax);
        cWp[i] = Dv * (tbx + Ax);
        cCm[i] = Dv * (tby - Ay);
        cCp[i] = Dv * (tby + Ay);
        A0[i]  = Dv * h[i] * ((f4)1.4f - tbx - tby);   // h0 == f both iters (K=2 lag)
        PqD[i] = Dv * (-0.4f);
        // vy = 0.5*(g1[c-1]-g1[c+1]); interior ux parts from register g
        f4 cm, cp;
        croll(g1[i], lm, lp, cm, cp);
        uv[i] = 0.5f * (cm - cp);
    }
    uv[0] -= 0.5f * g[1];                 // ux[0] = 0.5*(gL - g[1]); gL after barrier
    uv[1] += 0.5f * (g[0] - g[2]);
    uv[2] += 0.5f * (g[1] - g[3]);
    uv[3] += 0.5f * g[2];                 // ux[3] = 0.5*(g[2] - gR)
    __syncthreads();   // barrier A: GH, FH visible

    // ---- cE from ux edges ----
    f4 cE[NPT];
    {
        const f4 gL = vload(&GH[(NSTRIP + sl) * CC + c4]);  // g[w0-1] (wrap)
        const f4 gR = vload(&GH[sr * CC + c4]);             // g[w0+4] (wrap)
        cE[0] = PqD[0] * (uv[0] + 0.5f * gL);
        cE[1] = PqD[1] * uv[1];
        cE[2] = PqD[2] * uv[2];
        cE[3] = PqD[3] * (uv[3] - 0.5f * gR);
    }

    // ---- PDE iter 1 (h == f): interior W-neighbors in registers ----
    f4 hn[NPT];
    {
        const f4 hL = vload(&FH[(NSTRIP + sl) * CC + c4]);
        const f4 hR = vload(&FH[sr * CC + c4]);
        #pragma unroll
        for (int i = 0; i < NPT; ++i) {
            const f4 hm = (i == 0)       ? hL : h[i - 1];
            const f4 hp = (i == NPT - 1) ? hR : h[i + 1];
            f4 cm, cp;
            croll(h[i], lm, lp, cm, cp);
            hn[i] = A0[i] + cE[i] * h[i] + cWm[i] * hm + cWp[i] * hp
                  + cCm[i] * cm + cCp[i] * cp;
        }
    }
    vstore(&HHb[s * CC + c4],            hn[0]);
    vstore(&HHb[(NSTRIP + s) * CC + c4], hn[NPT - 1]);
    __syncthreads();   // barrier B: h1 edges visible

    // ---- PDE iter 2 ----
    f4 h2v[NPT];
    {
        const f4 hL = vload(&HHb[(NSTRIP + sl) * CC + c4]);
        const f4 hR = vload(&HHb[sr * CC + c4]);
        #pragma unroll
        for (int i = 0; i < NPT; ++i) {
            const f4 hm = (i == 0)       ? hL : hn[i - 1];
            const f4 hp = (i == NPT - 1) ? hR : hn[i + 1];
            f4 cm, cp;
            croll(hn[i], lm, lp, cm, cp);
            h2v[i] = A0[i] + cE[i] * hn[i] + cWm[i] * hm + cWp[i] * hp
                   + cCm[i] * cm + cCp[i] * cp;
        }
    }

    // ---- epilogue: BN + ReLU ----
    f4 s_o, b_o;
    BNFOLD(bn_out, s_o, b_o, 1.0f);
    #undef BNFOLD
    #pragma unroll
    for (int i = 0; i < NPT; ++i)
        vstore(out + rowbase + oc[i + 1], vrelu(h2v[i] * s_o + b_o));
}

extern "C" void kernel_launch(void* const* d_in, const int* in_sizes, int n_in,
                              void* d_out, int out_size, void* d_ws, size_t ws_size,
                              hipStream_t stream) {
    const float* s0   = (const float*)d_in[0];
    const float* kg   = (const float*)d_in[1];
    const float* kg1  = (const float*)d_in[2];
    const float* kDx  = (const float*)d_in[3];
    const float* kDy  = (const float*)d_in[4];
    const float* bng  = (const float*)d_in[5];
    const float* bng1 = (const float*)d_in[6];
    const float* bnDx = (const float*)d_in[7];
    const float* bnDy = (const float*)d_in[8];
    const float* bno  = (const float*)d_in[9];
    float* out = (float*)d_out;

    dim3 grid(16 * 128);   // one block per (batch, row), XCD-swizzled in-kernel
    dim3 block(BS);
    diffusion_fused<<<grid, block, 0, stream>>>(
        s0, kg, kg1, kDx, kDy, bng, bng1, bnDx, bnDy, bno, out);
}

// Round 7
// 151.111 us; speedup vs baseline: 3.6216x; 1.1339x over previous
//
#include <hip/hip_runtime.h>

#define HH 128
#define WW 128
#define CC 64
#define BS 512
#define RS (WW * CC)    // row stride in floats
#define NPT 4           // contiguous w-points per thread
#define NSTRIP 32       // strips per row (NSTRIP * NPT == WW)
#define ROWS 8          // image rows per block (grid = 16*128/ROWS = 256 = 1/CU)

typedef float f4 __attribute__((ext_vector_type(4)));

static __device__ __forceinline__ f4 vload(const float* p) {
    return *reinterpret_cast<const f4*>(p);
}
static __device__ __forceinline__ void vstore(float* p, f4 v) {
    *reinterpret_cast<f4*>(p) = v;
}
static __device__ __forceinline__ f4 vrelu(f4 a) {
    f4 r;
    #pragma unroll
    for (int i = 0; i < 4; ++i) r[i] = fmaxf(a[i], 0.f);
    return r;
}
static __device__ __forceinline__ f4 vrsq_eps(f4 a) {   // 1/sqrt(a+eps), HW v_rsq_f32
    f4 r;
    #pragma unroll
    for (int i = 0; i < 4; ++i) r[i] = __builtin_amdgcn_rsqf(a[i] + 1e-3f);
    return r;
}
static __device__ __forceinline__ f4 vrcp(f4 a) {       // 1/a, HW v_rcp_f32
    f4 r;
    #pragma unroll
    for (int i = 0; i < 4; ++i) r[i] = __builtin_amdgcn_rcpf(a[i]);
    return r;
}
// Channel-roll (c+-1 wrap over 64 ch) of an f4 held across a 16-lane cq group.
static __device__ __forceinline__ void croll(f4 v, int lm, int lp, f4& cm, f4& cp) {
    const float m3 = __shfl(v.w, lm);
    const float p0 = __shfl(v.x, lp);
    cm.x = m3;  cm.y = v.x; cm.z = v.y; cm.w = v.z;
    cp.x = v.y; cp.y = v.z; cp.z = v.w; cp.w = p0;
}

// async global->LDS DMA, 16 B/lane; LDS dest = wave-uniform base + lane*16 (m03/m97)
static __device__ __forceinline__ void gld_lds16(const float* g, float* l) {
    __builtin_amdgcn_global_load_lds(
        (const __attribute__((address_space(1))) void*)g,
        (__attribute__((address_space(3))) void*)l,
        16, 0, 0);
}
// copy one 32 KB image row into an LDS ring slot (4 x 1 KB chunks per wave)
static __device__ __forceinline__ void stage_row(const float* g, float* l,
                                                 int wv, int ln) {
    #pragma unroll
    for (int it = 0; it < 4; ++it) {
        const int off = (it * 8 + wv) * 256;   // float offset, wave-uniform
        gld_lds16(g + off + ln * 4, l + off);
    }
}

// 3 taps (one conv row) for all 4 kernels x 4 points, inputs from LDS ring.
template<bool CENTER>
static __device__ __forceinline__ void conv_taps(
    const float* R, const float* WTS, int kbase, const int* oc,
    bool zl, bool zr, int c4,
    f4* ag, f4* ag1, f4* adx, f4* ady, f4* h)
{
    f4 in[6];
    #pragma unroll
    for (int jj = 0; jj < 6; ++jj) in[jj] = vload(R + oc[jj]);
    if (zl) in[0] = (f4)0.f;     // zero pad, cndmask
    if (zr) in[5] = (f4)0.f;
    if (CENTER) {
        #pragma unroll
        for (int i = 0; i < NPT; ++i) h[i] = in[i + 1];   // f
    }
    #pragma unroll
    for (int dw = 0; dw < 3; ++dw) {
        const int kk = kbase + dw;
        const f4 wg  = vload(WTS + (0 * 9 + kk) * CC + c4);
        const f4 wg1 = vload(WTS + (1 * 9 + kk) * CC + c4);
        const f4 wdx = vload(WTS + (2 * 9 + kk) * CC + c4);
        const f4 wdy = vload(WTS + (3 * 9 + kk) * CC + c4);
        #pragma unroll
        for (int i = 0; i < NPT; ++i) {
            ag[i]  += in[dw + i] * wg;
            ag1[i] += in[dw + i] * wg1;
            adx[i] += in[dw + i] * wdx;
            ady[i] += in[dw + i] * wdy;
        }
    }
}

// NOTE (r2): never pin min-waves-per-EU -> catastrophic spill.
// NOTE (r4/r6): conv global-VMEM latency is the bottleneck; instr count is the currency.
// This round: rows LDS-resident via async DMA ring; 1 block/CU (LDS 139.5 KB),
// so VGPR is free up to 256 -> no spill cliff.
__global__ __launch_bounds__(BS) void diffusion_fused(
    const float* __restrict__ s0,
    const float* __restrict__ kg,  const float* __restrict__ kg1,
    const float* __restrict__ kDx, const float* __restrict__ kDy,
    const float* __restrict__ bng,  const float* __restrict__ bng1,
    const float* __restrict__ bnDx, const float* __restrict__ bnDy,
    const float* __restrict__ bn_out,
    float* __restrict__ out)
{
    __shared__ __attribute__((aligned(16))) float ring[3][RS];          // 96 KB input-row ring, slot(row x) = x%3
    __shared__ __attribute__((aligned(16))) float GH[2 * NSTRIP * CC];  // 16 KB g strip-edge halos
    __shared__ __attribute__((aligned(16))) float HHb[2 * NSTRIP * CC]; // 16 KB h1 strip-edge halos
    __shared__ __attribute__((aligned(16))) float WTS[4 * 9 * CC];      // 9 KB conv weights
    __shared__ __attribute__((aligned(16))) float BNF[10 * CC];         // 2.5 KB folded BN params

    const int t  = threadIdx.x;
    const int cq = t & 15;
    const int c4 = cq << 2;              // channels c4..c4+3
    const int s  = t >> 4;               // strip 0..31
    const int w0 = s << 2;               // output columns w0..w0+3
    const int l  = t & 63;
    const int wv = t >> 6;               // wave 0..7
    const int lm = (l & 48) | ((l + 15) & 15);   // channel-roll shuffle lanes
    const int lp = (l & 48) | ((l + 1)  & 15);
    const int sl = (s + NSTRIP - 1) & (NSTRIP - 1);
    const int sr = (s + 1) & (NSTRIP - 1);

    const int bid = blockIdx.x;
    const int img = bid >> 4;            // 16 row-groups per image
    const int r0  = (bid & 15) << 3;     // first row of this block's group
    const long imgbase = (long)img * HH * RS;

    // column offsets for the 6-column window w0-1 .. w0+4 (clamped; pad zeroed)
    const bool zl = (s == 0), zr = (s == NSTRIP - 1);
    int oc[6];
    oc[0] = (zl ? 0 : (w0 - 1)) * CC + c4;
    #pragma unroll
    for (int j = 1; j <= 4; ++j) oc[j] = (w0 + j - 1) * CC + c4;
    oc[5] = (zr ? (WW - 1) : (w0 + 4)) * CC + c4;
    const int wmo = ((w0 - 1) & (WW - 1)) * CC + c4;   // wrap left col (roll semantics)
    const int wpo = ((w0 + 4) & (WW - 1)) * CC + c4;   // wrap right col

    // ---- prologue: stage rows r0-1..r0+1, weights, BN folds ----
    if (r0 > 0)
        stage_row(s0 + imgbase + (long)(r0 - 1) * RS, ring[(r0 - 1) % 3], wv, l);
    stage_row(s0 + imgbase + (long)r0 * RS,       ring[r0 % 3],       wv, l);
    stage_row(s0 + imgbase + (long)(r0 + 1) * RS, ring[(r0 + 1) % 3], wv, l);

    {   // weights -> LDS (576 f4 slots)
        const float* wsrc[4] = { kg, kg1, kDx, kDy };
        #pragma unroll
        for (int base = 0; base < 576; base += BS) {
            const int slot = base + t;
            if (slot < 576) {
                const int q   = slot / 144;
                const int rem = slot - q * 144;
                const int kk  = rem >> 4;
                const int cc4 = (rem & 15) << 2;
                vstore(&WTS[(q * 9 + kk) * CC + cc4], vload(wsrc[q] + kk * CC + cc4));
            }
        }
    }
    if (s == 0) {   // BN folds: y = S*x + B (2*DT folded into Dx/Dy)
        #define BNF1(P, K, SC) { \
            const f4 ga = vload((P) + c4);       const f4 be = vload((P) + 64 + c4);  \
            const f4 mu = vload((P) + 128 + c4); const f4 va = vload((P) + 192 + c4); \
            const f4 sc0 = ga * vrsq_eps(va);                                         \
            vstore(&BNF[(2 * (K)) * CC + c4], sc0 * (SC));                            \
            vstore(&BNF[(2 * (K) + 1) * CC + c4], (be - mu * sc0) * (SC)); }
        BNF1(bng,    0, 1.0f);
        BNF1(bng1,   1, 1.0f);
        BNF1(bnDx,   2, 0.4f);
        BNF1(bnDy,   3, 0.4f);
        BNF1(bn_out, 4, 1.0f);
        #undef BNF1
    }
    __syncthreads();   // prologue staging + WTS/BNF visible

    // ---- row loop: 3 barriers/row; stage row gr+2 overlaps conv+coeffs ----
    for (int j = 0; j < ROWS; ++j) {
        const int gr = r0 + j;
        const bool rowm = (gr > 0), rowp = (gr < HH - 1);
        const float* Rm = ring[(gr + 2) % 3];   // row gr-1 (slot (gr-1)%3)
        const float* Rc = ring[gr % 3];         // row gr
        const float* Rp = ring[(gr + 1) % 3];   // row gr+1

        f4 ag[NPT], ag1[NPT], adx[NPT], ady[NPT], h[NPT];
        #pragma unroll
        for (int i = 0; i < NPT; ++i) {
            ag[i] = (f4)0.f; ag1[i] = (f4)0.f; adx[i] = (f4)0.f; ady[i] = (f4)0.f;
        }

        if (rowm) conv_taps<false>(Rm, WTS, 0, oc, zl, zr, c4, ag, ag1, adx, ady, h);
        __syncthreads();   // S: slot of row gr-1 fully consumed -> safe to overwrite
        if (j < ROWS - 1 && gr + 2 < HH)
            stage_row(s0 + imgbase + (long)(gr + 2) * RS, ring[(gr + 2) % 3], wv, l);

        conv_taps<true >(Rc, WTS, 3, oc, zl, zr, c4, ag, ag1, adx, ady, h);
        if (rowp) conv_taps<false>(Rp, WTS, 6, oc, zl, zr, c4, ag, ag1, adx, ady, h);

        // BN apply + g/g1; publish g strip edges
        const f4 s_g  = vload(&BNF[0 * CC + c4]), b_g  = vload(&BNF[1 * CC + c4]);
        const f4 s_g1 = vload(&BNF[2 * CC + c4]), b_g1 = vload(&BNF[3 * CC + c4]);
        const f4 s_dx = vload(&BNF[4 * CC + c4]), b_dx = vload(&BNF[5 * CC + c4]);
        const f4 s_dy = vload(&BNF[6 * CC + c4]), b_dy = vload(&BNF[7 * CC + c4]);
        f4 g[NPT], g1[NPT];
        #pragma unroll
        for (int i = 0; i < NPT; ++i) {
            g[i]  = vrelu(ag[i]  * s_g  + b_g );
            g1[i] = vrelu(ag1[i] * s_g1 + b_g1);
        }
        vstore(&GH[s * CC + c4],            g[0]);
        vstore(&GH[(NSTRIP + s) * CC + c4], g[NPT - 1]);

        // per-point PDE coefficients (verbatim r5 numerics)
        f4 cWm[NPT], cWp[NPT], cCm[NPT], cCp[NPT], A0[NPT], PqD[NPT], uv[NPT];
        #pragma unroll
        for (int i = 0; i < NPT; ++i) {
            const f4 tbx = vrelu(adx[i] * s_dx + b_dx);   // = 2*DT*Dx
            const f4 tby = vrelu(ady[i] * s_dy + b_dy);   // = 2*DT*Dy
            const f4 Dv  = vrcp((f4)1.f + tbx + tby);
            const f4 Ax  = g[i]  * 0.2f;
            const f4 Ay  = g1[i] * 0.2f;
            cWm[i] = Dv * (tbx - Ax);
            cWp[i] = Dv * (tbx + Ax);
            cCm[i] = Dv * (tby - Ay);
            cCp[i] = Dv * (tby + Ay);
            A0[i]  = Dv * h[i] * ((f4)1.4f - tbx - tby);  // h0 == f both iters (K=2 lag)
            PqD[i] = Dv * (-0.4f);
            f4 cm, cp;
            croll(g1[i], lm, lp, cm, cp);
            uv[i] = 0.5f * (cm - cp);                     // vy part
        }
        uv[0] -= 0.5f * g[1];
        uv[1] += 0.5f * (g[0] - g[2]);
        uv[2] += 0.5f * (g[1] - g[3]);
        uv[3] += 0.5f * g[2];
        __syncthreads();   // A: GH visible; stage DMA drained (row gr+2 ready)

        // cE from ux edges
        f4 cE[NPT];
        {
            const f4 gL = vload(&GH[(NSTRIP + sl) * CC + c4]);
            const f4 gR = vload(&GH[sr * CC + c4]);
            cE[0] = PqD[0] * (uv[0] + 0.5f * gL);
            cE[1] = PqD[1] * uv[1];
            cE[2] = PqD[2] * uv[2];
            cE[3] = PqD[3] * (uv[3] - 0.5f * gR);
        }

        // PDE iter 1 (h == f): edge W-neighbors straight from the ring (f row)
        f4 hn[NPT];
        {
            const f4 hL = vload(Rc + wmo);
            const f4 hR = vload(Rc + wpo);
            #pragma unroll
            for (int i = 0; i < NPT; ++i) {
                const f4 hm = (i == 0)       ? hL : h[i - 1];
                const f4 hp = (i == NPT - 1) ? hR : h[i + 1];
                f4 cm, cp;
                croll(h[i], lm, lp, cm, cp);
                hn[i] = A0[i] + cE[i] * h[i] + cWm[i] * hm + cWp[i] * hp
                      + cCm[i] * cm + cCp[i] * cp;
            }
        }
        vstore(&HHb[s * CC + c4],            hn[0]);
        vstore(&HHb[(NSTRIP + s) * CC + c4], hn[NPT - 1]);
        __syncthreads();   // B: h1 edges visible

        // PDE iter 2
        f4 h2v[NPT];
        {
            const f4 hL = vload(&HHb[(NSTRIP + sl) * CC + c4]);
            const f4 hR = vload(&HHb[sr * CC + c4]);
            #pragma unroll
            for (int i = 0; i < NPT; ++i) {
                const f4 hm = (i == 0)       ? hL : hn[i - 1];
                const f4 hp = (i == NPT - 1) ? hR : hn[i + 1];
                f4 cm, cp;
                croll(hn[i], lm, lp, cm, cp);
                h2v[i] = A0[i] + cE[i] * hn[i] + cWm[i] * hm + cWp[i] * hp
                       + cCm[i] * cm + cCp[i] * cp;
            }
        }

        // epilogue: BN + ReLU
        const f4 s_o = vload(&BNF[8 * CC + c4]), b_o = vload(&BNF[9 * CC + c4]);
        const long rowout = imgbase + (long)gr * RS;
        #pragma unroll
        for (int i = 0; i < NPT; ++i)
            vstore(out + rowout + oc[i + 1], vrelu(h2v[i] * s_o + b_o));
    }
}

extern "C" void kernel_launch(void* const* d_in, const int* in_sizes, int n_in,
                              void* d_out, int out_size, void* d_ws, size_t ws_size,
                              hipStream_t stream) {
    const float* s0   = (const float*)d_in[0];
    const float* kg   = (const float*)d_in[1];
    const float* kg1  = (const float*)d_in[2];
    const float* kDx  = (const float*)d_in[3];
    const float* kDy  = (const float*)d_in[4];
    const float* bng  = (const float*)d_in[5];
    const float* bng1 = (const float*)d_in[6];
    const float* bnDx = (const float*)d_in[7];
    const float* bnDy = (const float*)d_in[8];
    const float* bno  = (const float*)d_in[9];
    float* out = (float*)d_out;

    dim3 grid(16 * (HH / ROWS));   // 256 blocks = 1 per CU, 8 rows each
    dim3 block(BS);
    diffusion_fused<<<grid, block, 0, stream>>>(
        s0, kg, kg1, kDx, kDy, bng, bng1, bnDx, bnDy, bno, out);
}